// Round 9
// baseline (133.214 us; speedup 1.0000x reference)
//
#include <hip/hip_runtime.h>

// ---------------------------------------------------------------------------
// 3-dispatch gather splat, COLUMN RECORDS, one wave per 8^3 tile, NO-LDS splat.
// History: R7 fat records; R8 9x bin_prep split; R9 LDS staging; R10 atomic
// padding (NULL); R11 column records; R12 stored f32 x-table (123.3); R13
// z-chunk ring (REVERTED: broke sibling-wave half-line write pairing);
// R14/15 depth-3 LDS pipeline (NULL: splat 46us).
// R16 (this round): splat was DS-PIPE THROUGHPUT-bound, not latency-bound:
// 69 broadcast ds_read_b128/wave x ~12cy (m134 per-inst floor, broadcast or
// not) x 128 waves/CU (DS pipe is per-CU, shared by 4 SIMDs) = 106K cy =
// 44us == measured. R2 cross-check: 61 reads -> 39us, measured 37. That's
// why every pipelining tweak was null. Fix: NO LDS AT ALL — records are
// wave-uniform, so broadcast via the VALU path: lane k global-loads record
// k's 12 dwords (3 x dwordx4, contiguous across lanes), hot loop does 12
// v_readlane_b32 -> SGPRs per record (per-SIMD pipe, ~2cy) + 15 VALU body
// with SGPR operands. Meta readlane first: z-miss (26%) skips the other 11.
// Record order (slot A,B,C ascending) identical to R12 -> absmax unchanged.
// Wave->tile mapping t=bid*4+wid unchanged (write-coalescing, R13 lesson).
// ws use ~50.5 MB.
// ---------------------------------------------------------------------------

#define NTILE 32768           // 32^3 tiles of 8^3 voxels
#define CAP   32              // records per center-slot: avg ~7.7, Poisson-safe
#define LOG2E 1.4426950408889634f

typedef unsigned long long ull;

struct __align__(16) Rec {    // 48 B, one per (gaussian, x-y column)
    float cy, cz, w2;         // voxel-space center y,z; exp2 scale
    unsigned meta;            // [0:8) mnz, [8:16) mxz_incl, [16:19) loy, [19:23) hiy
    float ex[8];              // clipped, intensity-folded x-table (zeros outside)
};

// ---- kernel 1: per-(Gaussian, tx, ty) column record ------------------------
__global__ __launch_bounds__(256) void bin_prep_kernel(
    const float* __restrict__ centers,
    const float* __restrict__ sigmas,
    const float* __restrict__ intens,
    int*  __restrict__ counts,
    Rec*  __restrict__ list,
    int N)
{
    int g = blockIdx.x * 256 + threadIdx.x;
    if (g >= N) return;
    int txi = blockIdx.y % 3;          // wave-uniform
    int tyi = blockIdx.y / 3;

    float cx = centers[3*g+0] * 255.0f;
    float cy = centers[3*g+1] * 255.0f;
    float cz = centers[3*g+2] * 255.0f;
    float sig = sigmas[g];
    float cut = 3.0f * sig * 255.0f;
    float cc[3] = {cx, cy, cz};
    int mn[3], mx[3];
    #pragma unroll
    for (int a = 0; a < 3; ++a) {
        mn[a] = (int)floorf(fmaxf(cc[a] - cut, 0.0f));
        mx[a] = (int)fminf(floorf(fminf(cc[a] + cut, 255.0f)) + 1.0f, 256.0f); // exclusive
    }
    float s255 = sig * 255.0f;
    float w2 = -0.5f * LOG2E / (s255 * s255);
    float inten = intens[g];

    int t0x = mn[0] >> 3, t1x = (mx[0] - 1) >> 3;
    int t0y = mn[1] >> 3, t1y = (mx[1] - 1) >> 3;

    int tx = t0x + txi; if (tx > t1x) return;
    int ty = t0y + tyi; if (ty > t1y) return;

    int ox = tx << 3, oy = ty << 3;
    int lox = max(mn[0] - ox, 0), hix = min(mx[0] - ox, 8);
    int loy = max(mn[1] - oy, 0), hiy = min(mx[1] - oy, 8);

    // clipped, intensity-folded x-table (identical math to verified fat path)
    float ex[8];
    #pragma unroll
    for (int i = 0; i < 8; ++i) {
        float d = (float)(ox + i) - cx;
        float v = exp2f(d * d * w2) * inten;
        ex[i] = (i >= lox && i < hix) ? v : 0.0f;
    }

    int tzc = ((int)cz) >> 3;                  // cz in [0,255) -> tzc in [0,31]
    int t = (tx << 10) | (ty << 5) | tzc;
    unsigned meta = (unsigned)mn[2] | ((unsigned)(mx[2] - 1) << 8)
                  | ((unsigned)loy << 16) | ((unsigned)hiy << 19);

    int slot = atomicAdd(&counts[t], 1);
    if (slot < CAP) {
        int4* p = (int4*)&list[(size_t)t * CAP + slot];
        p[0] = make_int4(__float_as_int(cy), __float_as_int(cz),
                         __float_as_int(w2), (int)meta);
        p[1] = make_int4(__float_as_int(ex[0]), __float_as_int(ex[1]),
                         __float_as_int(ex[2]), __float_as_int(ex[3]));
        p[2] = make_int4(__float_as_int(ex[4]), __float_as_int(ex[5]),
                         __float_as_int(ex[6]), __float_as_int(ex[7]));
    }
}

// ---- kernel 2: gather — one wave per tile, lane-distributed records --------
__global__ __launch_bounds__(256) void splat_main(
    const int*  __restrict__ counts,
    const Rec*  __restrict__ list,
    float* __restrict__ vol)
{
    int wid = threadIdx.x >> 6;
    int lane = threadIdx.x & 63;
    int t = __builtin_amdgcn_readfirstlane(blockIdx.x * 4 + wid);
    int ox = (t >> 10) << 3, oy = ((t >> 5) & 31) << 3, oz = (t & 31) << 3;
    int tz = t & 31;
    int ly = lane >> 3, lz = lane & 7;

    int c0 = (tz > 0)  ? counts[t - 1] : 0;  if (c0 > CAP) c0 = CAP;
    int c1 = counts[t];                       if (c1 > CAP) c1 = CAP;
    int c2 = (tz < 31) ? counts[t + 1] : 0;  if (c2 > CAP) c2 = CAP;
    int e1 = c0 + c1, ntot = e1 + c2;

    const int4* sA = (const int4*)(list + (long)(t - 1) * CAP);  // deref'd only if c0>0
    const int4* sB = (const int4*)(list + (long)t * CAP);
    const int4* sC = (const int4*)(list + (long)(t + 1) * CAP);  // deref'd only if c2>0

    // lane-distributed record registers: lane k holds record (k + 64*phase)
    int4 A0, A1, A2;
    auto load_rec = [&](int r) {
        const int4* src; int rr;
        if (r < c0)        { src = sA; rr = r; }
        else if (r < e1)   { src = sB; rr = r - c0; }
        else if (r < ntot) { src = sC; rr = r - e1; }
        else               { src = sB; rr = 0; }     // idle lane: safe in-bounds dummy
        A0 = src[rr * 3]; A1 = src[rr * 3 + 1]; A2 = src[rr * 3 + 2];
    };

    float fy = (float)(oy + ly);
    float fz = (float)(oz + lz);

    float acc[8];
    #pragma unroll
    for (int i = 0; i < 8; ++i) acc[i] = 0.0f;

    // broadcast record k from lane k via v_readlane (VALU pipe, per-SIMD) —
    // no DS-pipe traffic at all.
    auto body = [&](int k) {
        unsigned meta = (unsigned)__builtin_amdgcn_readlane(A0.w, k);
        int mnz  = (int)(meta & 0xFF);
        int mxzi = (int)((meta >> 8) & 0xFF);
        int loz = mnz - oz;      if (loz < 0) loz = 0;
        int hiz = mxzi + 1 - oz; if (hiz > 8) hiz = 8;
        if (loz < hiz) {                       // wave-uniform z-overlap branch
            int loy_ = (int)((meta >> 16) & 7);
            int hiy_ = (int)((meta >> 19) & 0xF);   // in [1,8]
            ull ym = ((~0ull) << (loy_ << 3)) & ((~0ull) >> (64 - (hiy_ << 3)));
            unsigned zpat = (0xFFu >> (8 - hiz)) & (0xFFu << loz);
            unsigned zrep = zpat * 0x01010101u;
            ull m = (((ull)zrep << 32) | (ull)zrep) & ym;

            float cyv = __int_as_float(__builtin_amdgcn_readlane(A0.x, k));
            float czv = __int_as_float(__builtin_amdgcn_readlane(A0.y, k));
            float w2v = __int_as_float(__builtin_amdgcn_readlane(A0.z, k));

            float dy = fy - cyv, dz = fz - czv;
            float e = exp2f(fmaf(dy, dy, dz * dz) * w2v);
            float em;
            asm("v_cndmask_b32 %0, 0, %1, %2" : "=v"(em) : "v"(e), "s"(m));

            float ex0 = __int_as_float(__builtin_amdgcn_readlane(A1.x, k));
            float ex1 = __int_as_float(__builtin_amdgcn_readlane(A1.y, k));
            float ex2 = __int_as_float(__builtin_amdgcn_readlane(A1.z, k));
            float ex3 = __int_as_float(__builtin_amdgcn_readlane(A1.w, k));
            float ex4 = __int_as_float(__builtin_amdgcn_readlane(A2.x, k));
            float ex5 = __int_as_float(__builtin_amdgcn_readlane(A2.y, k));
            float ex6 = __int_as_float(__builtin_amdgcn_readlane(A2.z, k));
            float ex7 = __int_as_float(__builtin_amdgcn_readlane(A2.w, k));

            acc[0] = fmaf(ex0, em, acc[0]);
            acc[1] = fmaf(ex1, em, acc[1]);
            acc[2] = fmaf(ex2, em, acc[2]);
            acc[3] = fmaf(ex3, em, acc[3]);
            acc[4] = fmaf(ex4, em, acc[4]);
            acc[5] = fmaf(ex5, em, acc[5]);
            acc[6] = fmaf(ex6, em, acc[6]);
            acc[7] = fmaf(ex7, em, acc[7]);
        }
    };

    // phase 1: records 0..min(ntot,64)-1 live in lane 0..63
    load_rec(lane);
    int n1 = ntot < 64 ? ntot : 64;
    for (int k = 0; k < n1; ++k) body(k);
    // phase 2 (Poisson tail, ~never taken but required for correctness)
    if (ntot > 64) {
        load_rec(lane + 64);
        int n2 = ntot - 64;
        for (int k = 0; k < n2; ++k) body(k);
    }

    int ybase = ((oy + ly) << 8) + (oz + lz);
    #pragma unroll
    for (int i = 0; i < 8; ++i)
        vol[((ox + i) << 16) + ybase] = acc[i];
}

// ---------------------------------------------------------------------------
extern "C" void kernel_launch(void* const* d_in, const int* in_sizes, int n_in,
                              void* d_out, int out_size, void* d_ws, size_t ws_size,
                              hipStream_t stream) {
    const float* centers = (const float*)d_in[0];   // (N,3)
    const float* sigmas  = (const float*)d_in[1];   // (N,)
    const float* intens  = (const float*)d_in[2];   // (N,)
    float* vol = (float*)d_out;                     // 256^3 fp32
    const int N = in_sizes[1];

    // workspace: counts 128KB | list NTILE*CAP*48B ~= 50.3 MiB
    char* ws = (char*)d_ws;
    int*  counts = (int*)ws;
    Rec*  list   = (Rec*)(ws + (size_t)NTILE * sizeof(int));

    hipMemsetAsync(counts, 0, (size_t)NTILE * sizeof(int), stream);

    int gblocks = (N + 255) / 256;
    bin_prep_kernel<<<dim3(gblocks, 9), 256, 0, stream>>>(centers, sigmas, intens,
                                                          counts, list, N);
    splat_main<<<NTILE / 4, 256, 0, stream>>>(counts, list, vol);
}